// Round 11
// baseline (28.761 us; speedup 1.0000x reference)
//
#include <hip/hip_runtime.h>
#include <math.h>

#define KFEAT 32768
#define GRID_N 33                // 33x33 grid, step = 1/32 of domain
#define NPTS (GRID_N * GRID_N)   // 1089 (LDS Fs size; odd-odd entries unused)
#define NQ 833                   // live points: NOT (odd gx & odd gy)
#define QSTRIDE 836              // NQ padded to multiple of 4
#define PTS_PER_BLOCK 8
#define PBLOCKS ((NQ + PTS_PER_BLOCK - 1) / PTS_PER_BLOCK)  // 105
#define SPLITK 8
#define NBLOCKS (PBLOCKS * SPLITK)  // 840
#define KG 4                     // hoisted float4 k-groups per thread
#define COUNTER_OFFSET 27648     // bytes; Fpart = 8*836*4 = 26752 B

#define INV2PI 0.15915494309189535f

// cos(2*pi*rev): v_fract (exact range reduction by periodicity) + v_cos
// (input in revolutions).
__device__ __forceinline__ float cos_rev(float rev) {
  float fr, c;
  asm("v_fract_f32 %0, %1" : "=v"(fr) : "v"(rev));
  asm("v_cos_f32 %0, %1" : "=v"(c) : "v"(fr));
  return c;
}

// Compacted point index q -> grid coords. Row pairs (even,odd) hold 33+17=50
// points: even rows keep all 33 gx, odd rows keep even gx only.
__device__ __forceinline__ void q_to_grid(int q, int& gx, int& gy) {
  int rp = q / 50;
  int rem = q - 50 * rp;
  if (rem < 33) { gy = 2 * rp;     gx = rem; }
  else          { gy = 2 * rp + 1; gx = (rem - 33) * 2; }
}

__device__ __forceinline__ int compact_bits(int v, int shift) {
  int r = (v >> shift) & 1;
  r |= ((v >> (shift + 2)) & 1) << 1;
  r |= ((v >> (shift + 4)) & 1) << 2;
  r |= ((v >> (shift + 6)) & 1) << 3;
  return r;
}

__device__ __forceinline__ float simpson_cell(const float* __restrict__ F,
                                              int d, int cell, float hx,
                                              float hy) {
  const int ix = compact_bits(cell, 0);
  const int iy = compact_bits(cell, 1);
  const int s = 5 - d;        // log2 of cell size in grid units
  const int h = 1 << (s - 1); // half-cell in grid units
  const int gx0 = ix << s, gx1 = gx0 + h, gx2 = gx0 + 2 * h;
  const int gy0 = iy << s, gy1 = gy0 + h, gy2 = gy0 + 2 * h;
  // point order: 0:(xl,yl) 1:(mx,yl) 2:(xr,yl) 3:(xl,my) 4:(xr,my)
  //              5:(xl,yr) 6:(mx,yr) 7:(xr,yr)  (center (gx1,gy1), the only
  // (odd,odd) point, has coefficient 0 in the reference formula -- skipped)
  const float f0 = F[gy0 * GRID_N + gx0];
  const float f1 = F[gy0 * GRID_N + gx1];
  const float f2 = F[gy0 * GRID_N + gx2];
  const float f3 = F[gy1 * GRID_N + gx0];
  const float f4 = F[gy1 * GRID_N + gx2];
  const float f5 = F[gy2 * GRID_N + gx0];
  const float f6 = F[gy2 * GRID_N + gx1];
  const float f7 = F[gy2 * GRID_N + gx2];
  return hx * hy * (1.0f / 12.0f) *
         (-(f0 + f2 + f5 + f7) + 4.0f * (f1 + f3 + f4 + f6));
}

// ---------------------------------------------------------------------------
// Fused kernel (R9 eval + relaxed-atomic ticket + winner-block combine).
// Phase 1 (840 blocks = 105 point-blocks x 8 K-splits): each thread owns
// KG=4 float4 k-groups (16 k's), all 16 loads hoisted, coefficients
// prescaled to revolutions; evaluates 8 of the 833 live grid points.
// Partials stored with agent-scope write-through atomic stores (8/block).
// Ticket: wave-0 vmcnt(0) + relaxed agent fetch_add (no wbl2/inv -- the
// R4 __threadfence regression). Winner block (saw NBLOCKS-1) re-reads
// Fpart with 64-bit agent-scope atomic loads (cache-bypass, 16 independent
// in flight per thread) and runs the Simpson/tree combine.
// ---------------------------------------------------------------------------
__global__ __launch_bounds__(256) void fused_kernel(
    const float4* __restrict__ w4, const float4* __restrict__ ax4,
    const float4* __restrict__ ay4, const float4* __restrict__ phi4,
    const float* __restrict__ xa_p, const float* __restrict__ xb_p,
    const float* __restrict__ ya_p, const float* __restrict__ yb_p,
    const float* __restrict__ eps_p, float* __restrict__ Fpart,
    int* __restrict__ counter, float* __restrict__ out) {
  const int tid = threadIdx.x;
  const int split = blockIdx.x & (SPLITK - 1);
  const int pblk = blockIdx.x >> 3;  // SPLITK == 8
  const float xa = xa_p[0], xb = xb_p[0];
  const float ya = ya_p[0], yb = yb_p[0];
  const float sx = (xb - xa) * (1.0f / 32.0f);
  const float sy = (yb - ya) * (1.0f / 32.0f);

  // ---------------- phase 1: eval partials ----------------
  {
    const int p0 = pblk * PTS_PER_BLOCK;
    float x[PTS_PER_BLOCK], y[PTS_PER_BLOCK];
#pragma unroll
    for (int j = 0; j < PTS_PER_BLOCK; ++j) {
      int q = min(p0 + j, NQ - 1);  // clamp; duplicate work, write guarded
      int gx, gy;
      q_to_grid(q, gx, gy);
      x[j] = fmaf((float)gx, sx, xa);
      y[j] = fmaf((float)gy, sy, ya);
    }

    // hoisted loads: KG k-groups x 4 arrays = 16 float4
    const int base4 = split * ((KFEAT / 4) / SPLITK);  // 1024 float4/split
    float4 A[KG], B[KG], P[KG], W[KG];
#pragma unroll
    for (int u = 0; u < KG; ++u) {
      const int idx = base4 + tid + 256 * u;
      A[u] = ax4[idx];
      B[u] = ay4[idx];
      P[u] = phi4[idx];
      W[u] = w4[idx];
    }
#pragma unroll
    for (int u = 0; u < KG; ++u) {  // prescale to revolutions
      A[u].x *= INV2PI; A[u].y *= INV2PI; A[u].z *= INV2PI; A[u].w *= INV2PI;
      B[u].x *= INV2PI; B[u].y *= INV2PI; B[u].z *= INV2PI; B[u].w *= INV2PI;
      P[u].x *= INV2PI; P[u].y *= INV2PI; P[u].z *= INV2PI; P[u].w *= INV2PI;
    }

    float acc[PTS_PER_BLOCK];
#pragma unroll
    for (int j = 0; j < PTS_PER_BLOCK; ++j) acc[j] = 0.0f;

#pragma unroll
    for (int u = 0; u < KG; ++u) {
#pragma unroll
      for (int j = 0; j < PTS_PER_BLOCK; ++j) {
        float r0 = fmaf(A[u].x, x[j], fmaf(B[u].x, y[j], P[u].x));
        float r1 = fmaf(A[u].y, x[j], fmaf(B[u].y, y[j], P[u].y));
        float r2 = fmaf(A[u].z, x[j], fmaf(B[u].z, y[j], P[u].z));
        float r3 = fmaf(A[u].w, x[j], fmaf(B[u].w, y[j], P[u].w));
        float s = fmaf(W[u].x, cos_rev(r0), fmaf(W[u].y, cos_rev(r1),
                  fmaf(W[u].z, cos_rev(r2), W[u].w * cos_rev(r3))));
        acc[j] += s;
      }
    }

    // Reduce each of the 8 accumulators across the 256-thread block.
    __shared__ float red[4][PTS_PER_BLOCK];  // [wave][point]
#pragma unroll
    for (int j = 0; j < PTS_PER_BLOCK; ++j) {
      float v = acc[j];
#pragma unroll
      for (int off = 32; off > 0; off >>= 1) v += __shfl_down(v, off, 64);
      if ((tid & 63) == 0) red[tid >> 6][j] = v;
    }
    __syncthreads();
    if (tid < PTS_PER_BLOCK) {
      const int j = tid;
      float v = red[0][j] + red[1][j] + red[2][j] + red[3][j];
      int q = p0 + j;
      if (q < NQ) {
        // agent-scope write-through: device-visible once vmcnt retires
        __hip_atomic_store(&Fpart[split * QSTRIDE + q], v, __ATOMIC_RELAXED,
                           __HIP_MEMORY_SCOPE_AGENT);
      }
    }
  }

  // ---------------- ticket: last finishing block combines ----------------
  // Stores above (tid<8, wave 0) and the ticket (tid 0, wave 0) share a
  // wave, so a wave-level vmcnt(0) is a sufficient release. No L2 flush.
  __shared__ int is_last;
  if (tid == 0) {
    asm volatile("s_waitcnt vmcnt(0)" ::: "memory");
    int old = __hip_atomic_fetch_add(counter, 1, __ATOMIC_RELAXED,
                                     __HIP_MEMORY_SCOPE_AGENT);
    is_last = (old == NBLOCKS - 1) ? 1 : 0;
  }
  __syncthreads();
  if (!is_last) return;

  // ---------------- phase 2: combine (winner block only) ----------------
  {
    __shared__ float Fsum[QSTRIDE];  // summed partials, compacted q order
    __shared__ float Fs[NPTS];  // grid-indexed; (odd,odd) entries never read
    __shared__ float S4[256], S3[64], S2[16], S1[4], S0[1];
    __shared__ float val3[64], val2[16], val1[4];
    const int t = tid;
    const float eps = *eps_p;
    const float HX = fabsf(xb - xa), HY = fabsf(yb - ya);

    // stage 1: 418 ull tasks; each sums 8 split rows with 64-bit
    // agent-scope (cache-bypass) loads -- up to 16 independent in flight.
    const unsigned long long* Fp8 = (const unsigned long long*)Fpart;
    for (int task = t; task < QSTRIDE / 2; task += 256) {
      float s0 = 0.0f, s1 = 0.0f;
#pragma unroll
      for (int sp = 0; sp < SPLITK; ++sp) {
        unsigned long long v = __hip_atomic_load(
            &Fp8[sp * (QSTRIDE / 2) + task], __ATOMIC_RELAXED,
            __HIP_MEMORY_SCOPE_AGENT);
        union { unsigned long long u; float f[2]; } cv;
        cv.u = v;
        s0 += cv.f[0];
        s1 += cv.f[1];
      }
      Fsum[2 * task] = s0;      // q >= NQ lanes hold garbage; never read
      Fsum[2 * task + 1] = s1;
    }
    __syncthreads();

    // stage 2: scatter compacted q -> grid position
    for (int q = t; q < NQ; q += 256) {
      int gx, gy;
      q_to_grid(q, gx, gy);
      Fs[gy * GRID_N + gx] = Fsum[q];
    }
    __syncthreads();

    // Simpson estimates at every depth
    S4[t] = simpson_cell(Fs, 4, t, HX * 0.0625f, HY * 0.0625f);
    if (t < 64) {
      S3[t] = simpson_cell(Fs, 3, t, HX * 0.125f, HY * 0.125f);
    } else if (t < 80) {
      S2[t - 64] = simpson_cell(Fs, 2, t - 64, HX * 0.25f, HY * 0.25f);
    } else if (t < 84) {
      S1[t - 80] = simpson_cell(Fs, 1, t - 80, HX * 0.5f, HY * 0.5f);
    } else if (t == 84) {
      S0[0] = simpson_cell(Fs, 0, 0, HX, HY);
    }
    __syncthreads();

    // d = 3 (MAX_DEPTH-1): truncate -> corrected unconditionally
    if (t < 64) {
      float sumq =
          ((S4[4 * t] + S4[4 * t + 1]) + S4[4 * t + 2]) + S4[4 * t + 3];
      // reference bug reproduced: quadrant 3 'whole' is quadrant 0's S
      float whole = ((t & 3) == 3) ? S3[t & ~3] : S3[t];
      float delta = sumq - whole;
      val3[t] = sumq + delta * (1.0f / 15.0f);
    }
    __syncthreads();

    // d = 2
    if (t < 16) {
      float sumq =
          ((S3[4 * t] + S3[4 * t + 1]) + S3[4 * t + 2]) + S3[4 * t + 3];
      float whole = ((t & 3) == 3) ? S2[t & ~3] : S2[t];
      float delta = sumq - whole;
      float corrected = sumq + delta * (1.0f / 15.0f);
      float child =
          ((val3[4 * t] + val3[4 * t + 1]) + val3[4 * t + 2]) + val3[4 * t + 3];
      float eps_d = eps * (1.0f / 16.0f);  // eps / 4^2
      val2[t] = (fabsf(delta) <= 15.0f * eps_d) ? corrected : child;
    }
    __syncthreads();

    // d = 1
    if (t < 4) {
      float sumq =
          ((S2[4 * t] + S2[4 * t + 1]) + S2[4 * t + 2]) + S2[4 * t + 3];
      float whole = ((t & 3) == 3) ? S1[t & ~3] : S1[t];
      float delta = sumq - whole;
      float corrected = sumq + delta * (1.0f / 15.0f);
      float child =
          ((val2[4 * t] + val2[4 * t + 1]) + val2[4 * t + 2]) + val2[4 * t + 3];
      float eps_d = eps * 0.25f;  // eps / 4^1
      val1[t] = (fabsf(delta) <= 15.0f * eps_d) ? corrected : child;
    }
    __syncthreads();

    // d = 0
    if (t == 0) {
      float sumq = ((S1[0] + S1[1]) + S1[2]) + S1[3];
      float delta = sumq - S0[0];
      float corrected = sumq + delta * (1.0f / 15.0f);
      float child = ((val1[0] + val1[1]) + val1[2]) + val1[3];
      out[0] = (fabsf(delta) <= 15.0f * eps) ? corrected : child;
    }
  }
}

extern "C" void kernel_launch(void* const* d_in, const int* in_sizes, int n_in,
                              void* d_out, int out_size, void* d_ws,
                              size_t ws_size, hipStream_t stream) {
  // input order: xa, xb, ya, yb, eps, w, ax, ay, phi
  const float* xa = (const float*)d_in[0];
  const float* xb = (const float*)d_in[1];
  const float* ya = (const float*)d_in[2];
  const float* yb = (const float*)d_in[3];
  const float* eps = (const float*)d_in[4];
  const float4* w4 = (const float4*)d_in[5];
  const float4* ax4 = (const float4*)d_in[6];
  const float4* ay4 = (const float4*)d_in[7];
  const float4* phi4 = (const float4*)d_in[8];
  float* out = (float*)d_out;
  float* Fpart = (float*)d_ws;  // SPLITK * QSTRIDE floats (26752 B)
  int* counter = (int*)((char*)d_ws + COUNTER_OFFSET);

  // Re-zero the ticket counter every call (graph memset node => also
  // re-zeroed on every timed replay).
  hipMemsetAsync(counter, 0, sizeof(int), stream);

  fused_kernel<<<NBLOCKS, 256, 0, stream>>>(w4, ax4, ay4, phi4, xa, xb, ya,
                                            yb, eps, Fpart, counter, out);
}

// Round 12
// 17.342 us; speedup vs baseline: 1.6585x; 1.6585x over previous
//
#include <hip/hip_runtime.h>
#include <math.h>

#define KFEAT 32768
#define GRID_N 33                // 33x33 grid, step = 1/32 of domain
#define NPTS (GRID_N * GRID_N)   // 1089 (LDS Fs size; odd-odd entries unused)
#define NQ 833                   // points actually used: NOT (odd gx & odd gy)
#define QSTRIDE 836              // NQ padded to multiple of 4
#define QGROUPS (QSTRIDE / 4)    // 209 float4 groups per split row
#define PTS_PER_BLOCK 8
#define PBLOCKS ((NQ + PTS_PER_BLOCK - 1) / PTS_PER_BLOCK)  // 105
#define SPLITK 8
#define KG 4                     // hoisted float4 k-groups per thread

#define INV2PI 0.15915494309189535f

// Compacted point index q -> grid coords. Row pairs (even,odd) hold 33+17=50
// points: even rows keep all 33 gx, odd rows keep even gx only (17 values).
__device__ __forceinline__ void q_to_grid(int q, int& gx, int& gy) {
  int rp = q / 50;           // magic-mul by compiler
  int rem = q - 50 * rp;
  if (rem < 33) { gy = 2 * rp;     gx = rem; }
  else          { gy = 2 * rp + 1; gx = (rem - 33) * 2; }
}

// cos(2*pi*rev): v_fract (exact range reduction by periodicity) + v_cos
// (input in revolutions).
__device__ __forceinline__ float cos_rev(float rev) {
  float fr, c;
  asm("v_fract_f32 %0, %1" : "=v"(fr) : "v"(rev));
  asm("v_cos_f32 %0, %1" : "=v"(c) : "v"(fr));
  return c;
}

// ---------------------------------------------------------------------------
// Kernel 1: evaluate f = sum_k w_k cos(ax_k x + ay_k y + phi_k) at the 833
// live grid points, split-K partials. grid = (105 point-blocks, 8 K-splits);
// each thread owns KG=4 float4 k-groups (16 k's), all 16 loads hoisted,
// coefficients prescaled to revolutions. Per item: 2 fma + fract + cos + fma.
// ---------------------------------------------------------------------------
__global__ __launch_bounds__(256) void eval_grid_kernel(
    const float4* __restrict__ w4, const float4* __restrict__ ax4,
    const float4* __restrict__ ay4, const float4* __restrict__ phi4,
    const float* __restrict__ xa_p, const float* __restrict__ xb_p,
    const float* __restrict__ ya_p, const float* __restrict__ yb_p,
    float* __restrict__ Fpart) {
  const int tid = threadIdx.x;
  const int pblk = blockIdx.x;
  const int split = blockIdx.y;
  const float xa = xa_p[0], xb = xb_p[0];
  const float ya = ya_p[0], yb = yb_p[0];
  const float sx = (xb - xa) * (1.0f / 32.0f);
  const float sy = (yb - ya) * (1.0f / 32.0f);

  const int p0 = pblk * PTS_PER_BLOCK;
  float x[PTS_PER_BLOCK], y[PTS_PER_BLOCK];
#pragma unroll
  for (int j = 0; j < PTS_PER_BLOCK; ++j) {
    int q = min(p0 + j, NQ - 1);  // clamp; duplicate work, write guarded
    int gx, gy;
    q_to_grid(q, gx, gy);
    x[j] = fmaf((float)gx, sx, xa);
    y[j] = fmaf((float)gy, sy, ya);
  }

  // ---- hoisted loads: KG k-groups x 4 arrays = 16 float4 ----
  const int base4 = split * ((KFEAT / 4) / SPLITK);  // 1024 float4 per split
  float4 A[KG], B[KG], P[KG], W[KG];
#pragma unroll
  for (int u = 0; u < KG; ++u) {
    const int idx = base4 + tid + 256 * u;
    A[u] = ax4[idx];
    B[u] = ay4[idx];
    P[u] = phi4[idx];
    W[u] = w4[idx];
  }
#pragma unroll
  for (int u = 0; u < KG; ++u) {  // prescale to revolutions
    A[u].x *= INV2PI; A[u].y *= INV2PI; A[u].z *= INV2PI; A[u].w *= INV2PI;
    B[u].x *= INV2PI; B[u].y *= INV2PI; B[u].z *= INV2PI; B[u].w *= INV2PI;
    P[u].x *= INV2PI; P[u].y *= INV2PI; P[u].z *= INV2PI; P[u].w *= INV2PI;
  }

  float acc[PTS_PER_BLOCK];
#pragma unroll
  for (int j = 0; j < PTS_PER_BLOCK; ++j) acc[j] = 0.0f;

#pragma unroll
  for (int u = 0; u < KG; ++u) {
#pragma unroll
    for (int j = 0; j < PTS_PER_BLOCK; ++j) {
      float r0 = fmaf(A[u].x, x[j], fmaf(B[u].x, y[j], P[u].x));
      float r1 = fmaf(A[u].y, x[j], fmaf(B[u].y, y[j], P[u].y));
      float r2 = fmaf(A[u].z, x[j], fmaf(B[u].z, y[j], P[u].z));
      float r3 = fmaf(A[u].w, x[j], fmaf(B[u].w, y[j], P[u].w));
      float s = fmaf(W[u].x, cos_rev(r0), fmaf(W[u].y, cos_rev(r1),
                fmaf(W[u].z, cos_rev(r2), W[u].w * cos_rev(r3))));
      acc[j] += s;
    }
  }

  // Reduce each of the 8 accumulators across the 256-thread block.
  __shared__ float red[4][PTS_PER_BLOCK];  // [wave][point]
#pragma unroll
  for (int j = 0; j < PTS_PER_BLOCK; ++j) {
    float v = acc[j];
#pragma unroll
    for (int off = 32; off > 0; off >>= 1) v += __shfl_down(v, off, 64);
    if ((tid & 63) == 0) red[tid >> 6][j] = v;
  }
  __syncthreads();
  if (tid < PTS_PER_BLOCK) {
    const int j = tid;
    float v = red[0][j] + red[1][j] + red[2][j] + red[3][j];
    int q = p0 + j;
    if (q < NQ) Fpart[split * QSTRIDE + q] = v;
  }
}

// ---------------------------------------------------------------------------
// Kernel 2: two-stage partial sum (418 threads x 4 independent float4 loads
// -> Fq[2][..] in LDS; then 833-thread scatter q->(gy*33+gx) into Fs), then
// Simpson cells at depths 0..4 + adaptive tree combine. Cell index uses the
// reference's interleaved quadrant order (base-4 digits, MSB = depth 1):
// ix = even bits compacted, iy = odd bits compacted (Morton).
// ---------------------------------------------------------------------------
__device__ __forceinline__ int compact_bits(int v, int shift) {
  int r = (v >> shift) & 1;
  r |= ((v >> (shift + 2)) & 1) << 1;
  r |= ((v >> (shift + 4)) & 1) << 2;
  r |= ((v >> (shift + 6)) & 1) << 3;
  return r;
}

__device__ __forceinline__ float simpson_cell(const float* __restrict__ F,
                                              int d, int cell, float hx,
                                              float hy) {
  const int ix = compact_bits(cell, 0);
  const int iy = compact_bits(cell, 1);
  const int s = 5 - d;        // log2 of cell size in grid units
  const int h = 1 << (s - 1); // half-cell in grid units
  const int gx0 = ix << s, gx1 = gx0 + h, gx2 = gx0 + 2 * h;
  const int gy0 = iy << s, gy1 = gy0 + h, gy2 = gy0 + 2 * h;
  // point order: 0:(xl,yl) 1:(mx,yl) 2:(xr,yl) 3:(xl,my) 4:(xr,my)
  //              5:(xl,yr) 6:(mx,yr) 7:(xr,yr)  (center (gx1,gy1) skipped --
  // the only (odd,odd) point, coeff 0 in the reference formula)
  const float f0 = F[gy0 * GRID_N + gx0];
  const float f1 = F[gy0 * GRID_N + gx1];
  const float f2 = F[gy0 * GRID_N + gx2];
  const float f3 = F[gy1 * GRID_N + gx0];
  const float f4 = F[gy1 * GRID_N + gx2];
  const float f5 = F[gy2 * GRID_N + gx0];
  const float f6 = F[gy2 * GRID_N + gx1];
  const float f7 = F[gy2 * GRID_N + gx2];
  return hx * hy * (1.0f / 12.0f) *
         (-(f0 + f2 + f5 + f7) + 4.0f * (f1 + f3 + f4 + f6));
}

__global__ __launch_bounds__(1024) void combine_kernel(
    const float* __restrict__ Fpart, const float* __restrict__ xa_p,
    const float* __restrict__ xb_p, const float* __restrict__ ya_p,
    const float* __restrict__ yb_p, const float* __restrict__ eps_p,
    float* __restrict__ out) {
  __shared__ alignas(16) float Fq[2][QSTRIDE];  // split-quad partial sums
  __shared__ float Fs[NPTS];   // grid-indexed; (odd,odd) entries never read
  __shared__ float S4[256], S3[64], S2[16], S1[4], S0[1];
  __shared__ float val3[64], val2[16], val1[4];
  const int t = threadIdx.x;
  const float xa = *xa_p, xb = *xb_p, ya = *ya_p, yb = *yb_p, eps = *eps_p;
  const float HX = fabsf(xb - xa), HY = fabsf(yb - ya);

  // --- stage 1: 418 threads x 4 independent float4 loads (one split-quad) ---
  if (t < 2 * QGROUPS) {
    const int quad = (t >= QGROUPS) ? 1 : 0;
    const int g = t - quad * QGROUPS;
    const float4* Fp4 = (const float4*)Fpart;
    float4 s = make_float4(0.0f, 0.0f, 0.0f, 0.0f);
#pragma unroll
    for (int sp = 0; sp < 4; ++sp) {
      float4 v = Fp4[(quad * 4 + sp) * QGROUPS + g];
      s.x += v.x; s.y += v.y; s.z += v.z; s.w += v.w;
    }
    ((float4*)&Fq[quad][0])[g] = s;  // pad floats (q>=833) garbage; never read
  }
  __syncthreads();

  // --- stage 2: merge quads + scatter compacted q -> grid position ---
  if (t < NQ) {
    float v = Fq[0][t] + Fq[1][t];
    int gx, gy;
    int rp = t / 50;
    int rem = t - 50 * rp;
    if (rem < 33) { gy = 2 * rp;     gx = rem; }
    else          { gy = 2 * rp + 1; gx = (rem - 33) * 2; }
    Fs[gy * GRID_N + gx] = v;
  }
  __syncthreads();

  // --- Simpson estimates at every depth ---
  if (t < 256) {
    S4[t] = simpson_cell(Fs, 4, t, HX * 0.0625f, HY * 0.0625f);
    if (t < 64) {
      S3[t] = simpson_cell(Fs, 3, t, HX * 0.125f, HY * 0.125f);
    } else if (t < 80) {
      S2[t - 64] = simpson_cell(Fs, 2, t - 64, HX * 0.25f, HY * 0.25f);
    } else if (t < 84) {
      S1[t - 80] = simpson_cell(Fs, 1, t - 80, HX * 0.5f, HY * 0.5f);
    } else if (t == 84) {
      S0[0] = simpson_cell(Fs, 0, 0, HX, HY);
    }
  }
  __syncthreads();

  // --- d = 3 (MAX_DEPTH-1): truncate -> corrected unconditionally ---
  if (t < 64) {
    float sumq = ((S4[4 * t] + S4[4 * t + 1]) + S4[4 * t + 2]) + S4[4 * t + 3];
    // reference bug reproduced: quadrant 3 'whole' is quadrant 0's S
    float whole = ((t & 3) == 3) ? S3[t & ~3] : S3[t];
    float delta = sumq - whole;
    val3[t] = sumq + delta * (1.0f / 15.0f);
  }
  __syncthreads();

  // --- d = 2 ---
  if (t < 16) {
    float sumq = ((S3[4 * t] + S3[4 * t + 1]) + S3[4 * t + 2]) + S3[4 * t + 3];
    float whole = ((t & 3) == 3) ? S2[t & ~3] : S2[t];
    float delta = sumq - whole;
    float corrected = sumq + delta * (1.0f / 15.0f);
    float child =
        ((val3[4 * t] + val3[4 * t + 1]) + val3[4 * t + 2]) + val3[4 * t + 3];
    float eps_d = eps * (1.0f / 16.0f);  // eps / 4^2
    val2[t] = (fabsf(delta) <= 15.0f * eps_d) ? corrected : child;
  }
  __syncthreads();

  // --- d = 1 ---
  if (t < 4) {
    float sumq = ((S2[4 * t] + S2[4 * t + 1]) + S2[4 * t + 2]) + S2[4 * t + 3];
    float whole = ((t & 3) == 3) ? S1[t & ~3] : S1[t];
    float delta = sumq - whole;
    float corrected = sumq + delta * (1.0f / 15.0f);
    float child =
        ((val2[4 * t] + val2[4 * t + 1]) + val2[4 * t + 2]) + val2[4 * t + 3];
    float eps_d = eps * 0.25f;  // eps / 4^1
    val1[t] = (fabsf(delta) <= 15.0f * eps_d) ? corrected : child;
  }
  __syncthreads();

  // --- d = 0 ---
  if (t == 0) {
    float sumq = ((S1[0] + S1[1]) + S1[2]) + S1[3];
    float delta = sumq - S0[0];
    float corrected = sumq + delta * (1.0f / 15.0f);
    float child = ((val1[0] + val1[1]) + val1[2]) + val1[3];
    out[0] = (fabsf(delta) <= 15.0f * eps) ? corrected : child;
  }
}

extern "C" void kernel_launch(void* const* d_in, const int* in_sizes, int n_in,
                              void* d_out, int out_size, void* d_ws,
                              size_t ws_size, hipStream_t stream) {
  // input order: xa, xb, ya, yb, eps, w, ax, ay, phi
  const float* xa = (const float*)d_in[0];
  const float* xb = (const float*)d_in[1];
  const float* ya = (const float*)d_in[2];
  const float* yb = (const float*)d_in[3];
  const float* eps = (const float*)d_in[4];
  const float4* w4 = (const float4*)d_in[5];
  const float4* ax4 = (const float4*)d_in[6];
  const float4* ay4 = (const float4*)d_in[7];
  const float4* phi4 = (const float4*)d_in[8];
  float* out = (float*)d_out;
  float* Fpart = (float*)d_ws;  // SPLITK * QSTRIDE floats (26752 B)

  dim3 grid(PBLOCKS, SPLITK);
  eval_grid_kernel<<<grid, 256, 0, stream>>>(w4, ax4, ay4, phi4, xa, xb, ya,
                                             yb, Fpart);
  combine_kernel<<<1, 1024, 0, stream>>>(Fpart, xa, xb, ya, yb, eps, out);
}